// Round 7
// baseline (2032.334 us; speedup 1.0000x reference)
//
#include <hip/hip_runtime.h>
#include <math.h>

#define TPB 1024   // 16 waves = 4/SIMD. QUAD LAYOUT (R5): thread =
                   // (qd = tid>>2 -> freqs 2qd,2qd+1 ; pos = tid&3 ->
                   // sections 4*pos..4*pos+3). 2 barriers/iter.
                   // R7: 8-padded gpart blocks (aligned 2-way f4 stores),
                   // b128 update reads on ALL 16 waves + 32-lane DPP
                   // ladder, K folded into batched-rcp recovery, L via
                   // log2(m.x * rcp(m.y)).

typedef float v2f __attribute__((ext_vector_type(2)));

static __device__ __forceinline__ v2f mk2(float x, float y) {
    v2f r; r.x = x; r.y = y; return r;
}
// Compiler-generated packed math only — NO hand-written v_pk_* asm (R5/R7).
static __device__ __forceinline__ v2f fma2(v2f a, v2f b, v2f c) {
    return __builtin_elementwise_fma(a, b, c);
}
// RAW v_rcp_f32 (~1 ulp): NR dropped (R16). R6 batches 4 section inverses
// through ONE product reciprocal (prefix/suffix recovery). R7 folds K into
// the recovery and derives L from the same reciprocal — all ~ulp-class
// perturbations (absmax stayed 8-16x under threshold; contracting).
static __device__ __forceinline__ v2f rcp2(v2f x) {
    v2f r;
    r.x = __builtin_amdgcn_rcpf(x.x);
    r.y = __builtin_amdgcn_rcpf(x.y);
    return r;
}

// Quad all-reduce of TWO independent values: xor1 (quad_perm [1,0,3,2])
// then xor2 ([2,3,0,1]). ALL 4 lanes end with the bit-identical total
// (pairwise tree + commutative adds). s_nops cover DPP read-after-VALU.
static __device__ __forceinline__ void quad_allsum2(float& a, float& b) {
    asm("s_nop 1\n\t"
        "v_add_f32 %0, %0, %0 quad_perm:[1,0,3,2] row_mask:0xf bank_mask:0xf bound_ctrl:0\n\t"
        "v_add_f32 %1, %1, %1 quad_perm:[1,0,3,2] row_mask:0xf bank_mask:0xf bound_ctrl:0\n\t"
        "s_nop 0\n\t"
        "v_add_f32 %0, %0, %0 quad_perm:[2,3,0,1] row_mask:0xf bank_mask:0xf bound_ctrl:0\n\t"
        "v_add_f32 %1, %1, %1 quad_perm:[2,3,0,1] row_mask:0xf bank_mask:0xf bound_ctrl:0"
        : "+v"(a), "+v"(b));
}

// SINGLE-stage cross-quad combine (R6): lanes l>=8 of each 16-row get
// v(l)+v(l-8): lanes 8..11 = quads{0,2}, 12..15 = quads{1,3} of the row.
__device__ __forceinline__ void red6_s8(float i0, float i1, float i2,
                                        float i3, float i4, float i5,
                                        float& o0, float& o1, float& o2,
                                        float& o3, float& o4, float& o5) {
    asm("s_nop 1\n\t"
        "v_add_f32 %0, %6, %6  row_shr:8 row_mask:0xf bank_mask:0xf bound_ctrl:0\n\t"
        "v_add_f32 %3, %9, %9  row_shr:8 row_mask:0xf bank_mask:0xf bound_ctrl:0\n\t"
        "v_add_f32 %1, %7, %7  row_shr:8 row_mask:0xf bank_mask:0xf bound_ctrl:0\n\t"
        "v_add_f32 %4, %10, %10 row_shr:8 row_mask:0xf bank_mask:0xf bound_ctrl:0\n\t"
        "v_add_f32 %2, %8, %8  row_shr:8 row_mask:0xf bank_mask:0xf bound_ctrl:0\n\t"
        "v_add_f32 %5, %11, %11 row_shr:8 row_mask:0xf bank_mask:0xf bound_ctrl:0"
        : "=&v"(o0), "=&v"(o1), "=&v"(o2), "=&v"(o3), "=&v"(o4), "=&v"(o5)
        : "v"(i0), "v"(i1), "v"(i2), "v"(i3), "v"(i4), "v"(i5));
}

// 32-lane-group reduction of FOUR values (R7 update): shr:1,2,4,8 then
// row_bcast:15 (row_mask 0xa: rows 1,3 receive lanes 15/47). Lanes 31 and
// 63 end with their 32-group totals. Round-robin -> 4-inst hazard spacing.
__device__ __forceinline__ void red4_g32(float& a, float& b,
                                         float& c, float& d) {
    asm("s_nop 1\n\t"
        "v_add_f32 %0, %0, %0 row_shr:1 row_mask:0xf bank_mask:0xf bound_ctrl:0\n\t"
        "v_add_f32 %1, %1, %1 row_shr:1 row_mask:0xf bank_mask:0xf bound_ctrl:0\n\t"
        "v_add_f32 %2, %2, %2 row_shr:1 row_mask:0xf bank_mask:0xf bound_ctrl:0\n\t"
        "v_add_f32 %3, %3, %3 row_shr:1 row_mask:0xf bank_mask:0xf bound_ctrl:0\n\t"
        "v_add_f32 %0, %0, %0 row_shr:2 row_mask:0xf bank_mask:0xf bound_ctrl:0\n\t"
        "v_add_f32 %1, %1, %1 row_shr:2 row_mask:0xf bank_mask:0xf bound_ctrl:0\n\t"
        "v_add_f32 %2, %2, %2 row_shr:2 row_mask:0xf bank_mask:0xf bound_ctrl:0\n\t"
        "v_add_f32 %3, %3, %3 row_shr:2 row_mask:0xf bank_mask:0xf bound_ctrl:0\n\t"
        "v_add_f32 %0, %0, %0 row_shr:4 row_mask:0xf bank_mask:0xf bound_ctrl:0\n\t"
        "v_add_f32 %1, %1, %1 row_shr:4 row_mask:0xf bank_mask:0xf bound_ctrl:0\n\t"
        "v_add_f32 %2, %2, %2 row_shr:4 row_mask:0xf bank_mask:0xf bound_ctrl:0\n\t"
        "v_add_f32 %3, %3, %3 row_shr:4 row_mask:0xf bank_mask:0xf bound_ctrl:0\n\t"
        "v_add_f32 %0, %0, %0 row_shr:8 row_mask:0xf bank_mask:0xf bound_ctrl:0\n\t"
        "v_add_f32 %1, %1, %1 row_shr:8 row_mask:0xf bank_mask:0xf bound_ctrl:0\n\t"
        "v_add_f32 %2, %2, %2 row_shr:8 row_mask:0xf bank_mask:0xf bound_ctrl:0\n\t"
        "v_add_f32 %3, %3, %3 row_shr:8 row_mask:0xf bank_mask:0xf bound_ctrl:0\n\t"
        "v_add_f32 %0, %0, %0 row_bcast:15 row_mask:0xa bank_mask:0xf\n\t"
        "v_add_f32 %1, %1, %1 row_bcast:15 row_mask:0xa bank_mask:0xf\n\t"
        "v_add_f32 %2, %2, %2 row_bcast:15 row_mask:0xa bank_mask:0xf\n\t"
        "v_add_f32 %3, %3, %3 row_bcast:15 row_mask:0xa bank_mask:0xf"
        : "+v"(a), "+v"(b), "+v"(c), "+v"(d));
}

// coefficient k (0..5 = b0,b1,b2,a0,a1,a2) -> paired column in
// [b0 a0 b1 a1 b2 a2]: b0,b1,b2 -> 0,2,4 ; a0,a1,a2 -> 1,3,5
__device__ __forceinline__ int cmap(int k) {
    return (k < 3) ? 2 * k : 2 * k - 5;
}

// GPAD=132 (per 32-LANE-PHASE bank derivation, R3/R4 method; 132/4=33≡1 mod 8
// so quad = (row + col/4) mod 8):
//  - backward f4 stores (16 writers/phase, rows 8w..8w+3 x pos 0..3, col
//    8*(4sl+pos)): quad = (row + 2pos) mod 8 (+const) -> each quad exactly
//    2x = the 256B/128B-sweep MINIMUM -> optimal. All f4 aligned (col%4==0).
//  - update b128 reads (col 4c, c uniform per phase, rows j+32i):
//    quad = (j + c) mod 8, j=0..31 -> perfect 4-way = the 512B minimum.
//  - 132*4 = 528 ≡ 0 mod 16: row starts 16B-aligned (R13).
#define GPAD 132

__global__
__attribute__((amdgpu_flat_work_group_size(TPB, TPB), amdgpu_waves_per_eu(4, 4)))
void sgd_filter(const float* __restrict__ sos_in,
                const float* __restrict__ target,
                float* __restrict__ out) {
    // 16 sections x 6 floats, PAIRED: [b0 a0 b1 a1 b2 a2] per section.
    __shared__ __align__(16) float sos[96];
    // 128 rows (row = 2*(tid>>4) + quad-parity, a 4-freq group); section
    // blocks of 8 cols at 8*(4*sl+pos): [b0 a0 b1 a1 b2 a2 0 0].
    __shared__ __align__(16) float gpart[128][GPAD];

    const int tid = threadIdx.x;
    const int qd  = tid >> 2;      // freq group: freqs 2qd, 2qd+1
    const int pos = tid & 3;       // section group: 4*pos .. 4*pos+3
    const float* secbase = &sos[pos * 24];

    if (tid < 96) sos[(tid / 6) * 6 + cmap(tid % 6)] = sos_in[tid];

    // Update identity (R7): thread (c = tid>>5 coeff-quad, j = tid&31 row
    // slice); ALL 16 waves participate. Owner lanes 31/63 hold 4 running
    // coefficients in registers. slot = c>>1 -> section 4*(slot&3)+(slot>>2);
    // h = c&1 selects (b0,a0,b1,a1) vs (b2,a2,0,0).
    const int c    = tid >> 5;
    const int j    = tid & 31;
    const int slot = c >> 1;
    const int h    = c & 1;
    const int us   = 4 * (slot & 3) + (slot >> 2);
    const bool owner = ((tid & 31) == 31);
    const float* urp = &gpart[j][4 * c];
    float k0 = 0.f, k1 = 0.f, k2 = 0.f, k3 = 0.f;
    if (owner) {
        if (h == 0) {
            k0 = sos_in[6 * us + 0]; k1 = sos_in[6 * us + 3];
            k2 = sos_in[6 * us + 1]; k3 = sos_in[6 * us + 4];
        } else {
            k0 = sos_in[6 * us + 2]; k1 = sos_in[6 * us + 5];
        }
    }

    // Per-thread frequency constants (two freqs)
    const double step = 3.14159265358979323846 / 511.0;
    const float w0 = (float)((double)(2 * qd) * step);
    const float w1 = (float)((double)(2 * qd + 1) * step);
    const float c10 = cosf(w0), s10 = -sinf(w0);
    const float c20 = c10 * c10 - s10 * s10, s20 = 2.0f * c10 * s10;
    const float c11 = cosf(w1), s11 = -sinf(w1);
    const float c21 = c11 * c11 - s11 * s11, s21 = 2.0f * c11 * s11;
    const float2 tg = *(const float2*)&target[2 * qd];
    const float KC = 40.0f / (512.0f * 2.302585092994046f); // 40/(n*ln10)

    const v2f c1v0 = mk2(c10, c10), s1v0 = mk2(s10, s10);
    const v2f c2v0 = mk2(c20, c20), s2v0 = mk2(s20, s20);
    const v2f c1v1 = mk2(c11, c11), s1v1 = mk2(s11, s11);
    const v2f c2v1 = mk2(c21, c21), s2v1 = mk2(s21, s21);

    __syncthreads();

    // 4 sections x 2 freqs: Re, Im, n; W = K/n after folded recovery.
    v2f RA0, RA1, RA2, RA3, IA0, IA1, IA2, IA3;
    v2f RB0, RB1, RB2, RB3, IB0, IB1, IB2, IB3;
    v2f NA0, NA1, NA2, NA3, NB0, NB1, NB2, NB3;

// One section, BOTH freqs (coefficient pair regs shared). n kept; no rcp.
#define SEC_EVAL(sl, BA0, BA1, BA2)                                         \
    {                                                                       \
        const v2f ba0 = BA0, ba1 = BA1, ba2 = BA2;                          \
        RA##sl = fma2(ba2, c2v0, fma2(ba1, c1v0, ba0));                     \
        IA##sl = fma2(ba2, s2v0, ba1 * s1v0);                               \
        NA##sl = fma2(RA##sl, RA##sl, IA##sl * IA##sl);                     \
        RB##sl = fma2(ba2, c2v1, fma2(ba1, c1v1, ba0));                     \
        IB##sl = fma2(ba2, s2v1, ba1 * s1v1);                               \
        NB##sl = fma2(RB##sl, RB##sl, IB##sl * IB##sl);                     \
    }

// Backward: W = K/n already folded (R7) -> per freq just P = W*R, Q = W*I;
// freq-pair combine; ONE stride-8 DPP per value. Writers = lanes
// (tid&15)>=8; row = 2*(tid>>4) + quad-parity; col block 8*(4*sl+pos).
// Two ALIGNED f4 stores in PAIRED order: (b0,a0,b1,a1) and (b2,a2,0,0).
#define SEC_BWD(sl)                                                         \
    {                                                                       \
        const v2f PA = WA##sl * RA##sl;                                     \
        const v2f QA = WA##sl * IA##sl;                                     \
        const v2f PB = WB##sl * RB##sl;                                     \
        const v2f QB = WB##sl * IB##sl;                                     \
        const v2f P  = PA + PB;                                             \
        const v2f G1 = fma2(c1v0, PA, s1v0 * QA) + fma2(c1v1, PB, s1v1 * QB);\
        const v2f G2 = fma2(c2v0, PA, s2v0 * QA) + fma2(c2v1, PB, s2v1 * QB);\
        float g0, g1, g2, g3, g4, g5;                                       \
        red6_s8(P.x, G1.x, G2.x, P.y, G1.y, G2.y,                           \
                g0, g1, g2, g3, g4, g5);                                    \
        if ((tid & 15) >= 8) {                                              \
            float* p = &gpart[((tid >> 4) << 1) | ((tid >> 2) & 1)]         \
                             [8 * (4 * (sl) + pos)];                        \
            *(float4*)p       = make_float4(g0, g3, g1, g4);                \
            *(float4*)(p + 4) = make_float4(g2, g5, 0.0f, 0.0f);            \
        }                                                                   \
    }

    for (int it = 0; it < 1000; ++it) {
        // ---- forward: 6 b128 broadcast loads cover my 4 sections ----
        const float4 q0 = *(const float4*)(secbase + 0);
        const float4 q1 = *(const float4*)(secbase + 4);
        const float4 q2 = *(const float4*)(secbase + 8);
        const float4 q3 = *(const float4*)(secbase + 12);
        const float4 q4 = *(const float4*)(secbase + 16);
        const float4 q5 = *(const float4*)(secbase + 20);
        SEC_EVAL(0, mk2(q0.x, q0.y), mk2(q0.z, q0.w), mk2(q1.x, q1.y))
        SEC_EVAL(1, mk2(q1.z, q1.w), mk2(q2.x, q2.y), mk2(q2.z, q2.w))
        SEC_EVAL(2, mk2(q3.x, q3.y), mk2(q3.z, q3.w), mk2(q4.x, q4.y))
        SEC_EVAL(3, mk2(q4.z, q4.w), mk2(q5.x, q5.y), mk2(q5.z, q5.w))

        // ---- products + reciprocal; L = log2(m.x * rcp(m.y)) (R7) ----
        const v2f tA01 = NA0 * NA1, tA23 = NA2 * NA3;
        const v2f mA   = tA01 * tA23;
        const v2f iA   = rcp2(mA);
        const v2f tB01 = NB0 * NB1, tB23 = NB2 * NB3;
        const v2f mB   = tB01 * tB23;
        const v2f iB   = rcp2(mB);
        float L0 = __builtin_amdgcn_logf(mA.x * iA.y);
        float L1 = __builtin_amdgcn_logf(mB.x * iB.y);

        // Quad butterfly: every lane gets the bit-identical 16-section total.
        quad_allsum2(L0, L1);

        const float mag0   = __builtin_amdgcn_exp2f(0.5f * L0);
        const float magpe0 = mag0 + 1e-8f;
        const float indB0  = 6.020599913279624f * __builtin_amdgcn_logf(magpe0);
        const float K0 = KC * (indB0 - tg.x) * mag0 * __builtin_amdgcn_rcpf(magpe0);
        const float mag1   = __builtin_amdgcn_exp2f(0.5f * L1);
        const float magpe1 = mag1 + 1e-8f;
        const float indB1  = 6.020599913279624f * __builtin_amdgcn_logf(magpe1);
        const float K1 = KC * (indB1 - tg.y) * mag1 * __builtin_amdgcn_rcpf(magpe1);
        const v2f KK0 = mk2(K0, -K0);   // A-side gradient sign folded here
        const v2f KK1 = mk2(K1, -K1);

        // ---- K folded into batched recovery: W = K/n per section ----
        const v2f jA   = KK0 * iA;
        const v2f jA01 = jA * tA23, jA23 = jA * tA01;
        const v2f WA0 = jA01 * NA1, WA1 = jA01 * NA0;
        const v2f WA2 = jA23 * NA3, WA3 = jA23 * NA2;
        const v2f jB   = KK1 * iB;
        const v2f jB01 = jB * tB23, jB23 = jB * tB01;
        const v2f WB0 = jB01 * NB1, WB1 = jB01 * NB0;
        const v2f WB2 = jB23 * NB3, WB3 = jB23 * NB2;

        // ---- backward: 4 sections, freq-pair add + 1-stage DPP, store ----
        SEC_BWD(0) SEC_BWD(1) SEC_BWD(2) SEC_BWD(3)
        __syncthreads();

        // ---- update (R7): ALL 16 waves; 4 b128 reads (rows j+32i, col 4c,
        //      perfect 4-way), pairwise v4 sum, 32-lane DPP ladder; owner
        //      lanes 31/63 apply SGD in-register and write sos as f2s ----
        {
            const float4 p0 = *(const float4*)urp;
            const float4 p1 = *(const float4*)(urp + 32 * GPAD);
            const float4 p2 = *(const float4*)(urp + 64 * GPAD);
            const float4 p3 = *(const float4*)(urp + 96 * GPAD);
            float t0 = (p0.x + p1.x) + (p2.x + p3.x);
            float t1 = (p0.y + p1.y) + (p2.y + p3.y);
            float t2 = (p0.z + p1.z) + (p2.z + p3.z);
            float t3 = (p0.w + p1.w) + (p2.w + p3.w);
            red4_g32(t0, t1, t2, t3);
            if (owner) {
                k0 = fmaf(-0.1f, t0, k0);
                k1 = fmaf(-0.1f, t1, k1);
                k2 = fmaf(-0.1f, t2, k2);
                k3 = fmaf(-0.1f, t3, k3);
                if (h == 0) {
                    *(float2*)&sos[6 * us]     = make_float2(k0, k1);
                    *(float2*)&sos[6 * us + 2] = make_float2(k2, k3);
                } else {
                    *(float2*)&sos[6 * us + 4] = make_float2(k0, k1);
                }
            }
        }
        __syncthreads();
    }

    if (owner) {
        if (h == 0) {
            out[6 * us + 0] = k0; out[6 * us + 3] = k1;
            out[6 * us + 1] = k2; out[6 * us + 4] = k3;
        } else {
            out[6 * us + 2] = k0; out[6 * us + 5] = k1;
        }
    }
}

extern "C" void kernel_launch(void* const* d_in, const int* in_sizes, int n_in,
                              void* d_out, int out_size, void* d_ws, size_t ws_size,
                              hipStream_t stream) {
    const float* sos_in = (const float*)d_in[0];
    const float* target = (const float*)d_in[1];
    float* outp = (float*)d_out;
    hipLaunchKernelGGL(sgd_filter, dim3(1), dim3(TPB), 0, stream, sos_in, target, outp);
}

// Round 9
// 1960.179 us; speedup vs baseline: 1.0368x; 1.0368x over previous
//
#include <hip/hip_runtime.h>
#include <math.h>

#define TPB 1024   // 16 waves = 4/SIMD. QUAD LAYOUT (R5): thread =
                   // (qd = tid>>2 -> freqs 2qd,2qd+1 ; pos = tid&3 ->
                   // sections 4*pos..4*pos+3). 2 barriers/iter.
                   // R9: EXACT R7 K-chain restored (R8's eps-drop FAILED:
                   // absmax 9.25 — the 1e-8 eps is semantics, not noise).
                   // Kept from R8: f2 backward tail stores, packed v4f
                   // update adds. New: G1/G2 as 4-deep fma chains.

typedef float v2f __attribute__((ext_vector_type(2)));
typedef float v4f __attribute__((ext_vector_type(4)));

static __device__ __forceinline__ v2f mk2(float x, float y) {
    v2f r; r.x = x; r.y = y; return r;
}
// Compiler-generated packed math only — NO hand-written v_pk_* asm (R5/R7).
static __device__ __forceinline__ v2f fma2(v2f a, v2f b, v2f c) {
    return __builtin_elementwise_fma(a, b, c);
}
// RAW v_rcp_f32 (~1 ulp): NR dropped (R16). R6 batches 4 section inverses
// through ONE product reciprocal (prefix/suffix recovery). R7 folds K into
// the recovery. The dB chain keeps its 1e-8 eps EXACTLY (R8 lesson).
static __device__ __forceinline__ v2f rcp2(v2f x) {
    v2f r;
    r.x = __builtin_amdgcn_rcpf(x.x);
    r.y = __builtin_amdgcn_rcpf(x.y);
    return r;
}

// Quad all-reduce of TWO independent values: xor1 (quad_perm [1,0,3,2])
// then xor2 ([2,3,0,1]). ALL 4 lanes end with the bit-identical total
// (pairwise tree + commutative adds). s_nops cover DPP read-after-VALU.
static __device__ __forceinline__ void quad_allsum2(float& a, float& b) {
    asm("s_nop 1\n\t"
        "v_add_f32 %0, %0, %0 quad_perm:[1,0,3,2] row_mask:0xf bank_mask:0xf bound_ctrl:0\n\t"
        "v_add_f32 %1, %1, %1 quad_perm:[1,0,3,2] row_mask:0xf bank_mask:0xf bound_ctrl:0\n\t"
        "s_nop 0\n\t"
        "v_add_f32 %0, %0, %0 quad_perm:[2,3,0,1] row_mask:0xf bank_mask:0xf bound_ctrl:0\n\t"
        "v_add_f32 %1, %1, %1 quad_perm:[2,3,0,1] row_mask:0xf bank_mask:0xf bound_ctrl:0"
        : "+v"(a), "+v"(b));
}

// SINGLE-stage cross-quad combine (R6): lanes l>=8 of each 16-row get
// v(l)+v(l-8): lanes 8..11 = quads{0,2}, 12..15 = quads{1,3} of the row.
__device__ __forceinline__ void red6_s8(float i0, float i1, float i2,
                                        float i3, float i4, float i5,
                                        float& o0, float& o1, float& o2,
                                        float& o3, float& o4, float& o5) {
    asm("s_nop 1\n\t"
        "v_add_f32 %0, %6, %6  row_shr:8 row_mask:0xf bank_mask:0xf bound_ctrl:0\n\t"
        "v_add_f32 %3, %9, %9  row_shr:8 row_mask:0xf bank_mask:0xf bound_ctrl:0\n\t"
        "v_add_f32 %1, %7, %7  row_shr:8 row_mask:0xf bank_mask:0xf bound_ctrl:0\n\t"
        "v_add_f32 %4, %10, %10 row_shr:8 row_mask:0xf bank_mask:0xf bound_ctrl:0\n\t"
        "v_add_f32 %2, %8, %8  row_shr:8 row_mask:0xf bank_mask:0xf bound_ctrl:0\n\t"
        "v_add_f32 %5, %11, %11 row_shr:8 row_mask:0xf bank_mask:0xf bound_ctrl:0"
        : "=&v"(o0), "=&v"(o1), "=&v"(o2), "=&v"(o3), "=&v"(o4), "=&v"(o5)
        : "v"(i0), "v"(i1), "v"(i2), "v"(i3), "v"(i4), "v"(i5));
}

// 32-lane-group reduction of FOUR values (R7 update): shr:1,2,4,8 then
// row_bcast:15 (row_mask 0xa: rows 1,3 receive lanes 15/47). Lanes 31 and
// 63 end with their 32-group totals. Round-robin -> 4-inst hazard spacing.
__device__ __forceinline__ void red4_g32(float& a, float& b,
                                         float& c, float& d) {
    asm("s_nop 1\n\t"
        "v_add_f32 %0, %0, %0 row_shr:1 row_mask:0xf bank_mask:0xf bound_ctrl:0\n\t"
        "v_add_f32 %1, %1, %1 row_shr:1 row_mask:0xf bank_mask:0xf bound_ctrl:0\n\t"
        "v_add_f32 %2, %2, %2 row_shr:1 row_mask:0xf bank_mask:0xf bound_ctrl:0\n\t"
        "v_add_f32 %3, %3, %3 row_shr:1 row_mask:0xf bank_mask:0xf bound_ctrl:0\n\t"
        "v_add_f32 %0, %0, %0 row_shr:2 row_mask:0xf bank_mask:0xf bound_ctrl:0\n\t"
        "v_add_f32 %1, %1, %1 row_shr:2 row_mask:0xf bank_mask:0xf bound_ctrl:0\n\t"
        "v_add_f32 %2, %2, %2 row_shr:2 row_mask:0xf bank_mask:0xf bound_ctrl:0\n\t"
        "v_add_f32 %3, %3, %3 row_shr:2 row_mask:0xf bank_mask:0xf bound_ctrl:0\n\t"
        "v_add_f32 %0, %0, %0 row_shr:4 row_mask:0xf bank_mask:0xf bound_ctrl:0\n\t"
        "v_add_f32 %1, %1, %1 row_shr:4 row_mask:0xf bank_mask:0xf bound_ctrl:0\n\t"
        "v_add_f32 %2, %2, %2 row_shr:4 row_mask:0xf bank_mask:0xf bound_ctrl:0\n\t"
        "v_add_f32 %3, %3, %3 row_shr:4 row_mask:0xf bank_mask:0xf bound_ctrl:0\n\t"
        "v_add_f32 %0, %0, %0 row_shr:8 row_mask:0xf bank_mask:0xf bound_ctrl:0\n\t"
        "v_add_f32 %1, %1, %1 row_shr:8 row_mask:0xf bank_mask:0xf bound_ctrl:0\n\t"
        "v_add_f32 %2, %2, %2 row_shr:8 row_mask:0xf bank_mask:0xf bound_ctrl:0\n\t"
        "v_add_f32 %3, %3, %3 row_shr:8 row_mask:0xf bank_mask:0xf bound_ctrl:0\n\t"
        "v_add_f32 %0, %0, %0 row_bcast:15 row_mask:0xa bank_mask:0xf\n\t"
        "v_add_f32 %1, %1, %1 row_bcast:15 row_mask:0xa bank_mask:0xf\n\t"
        "v_add_f32 %2, %2, %2 row_bcast:15 row_mask:0xa bank_mask:0xf\n\t"
        "v_add_f32 %3, %3, %3 row_bcast:15 row_mask:0xa bank_mask:0xf"
        : "+v"(a), "+v"(b), "+v"(c), "+v"(d));
}

// coefficient k (0..5 = b0,b1,b2,a0,a1,a2) -> paired column in
// [b0 a0 b1 a1 b2 a2]: b0,b1,b2 -> 0,2,4 ; a0,a1,a2 -> 1,3,5
__device__ __forceinline__ int cmap(int k) {
    return (k < 3) ? 2 * k : 2 * k - 5;
}

// GPAD=132 (per 32-LANE-PHASE bank derivation, R3/R4 method; 132/4=33≡1 mod 8
// so quad = (row + col/4) mod 8):
//  - backward f4 stores (16 writers/phase, rows 8w..8w+3 x pos 0..3, col
//    8*(4sl+pos)): quad = (row + 2pos) mod 8 (+const) -> each quad exactly
//    2x = the sweep MINIMUM. f2 tail at +4: same 2-way. All aligned (R13).
//  - update b128 reads (col 4c, c uniform per phase, rows j+32i):
//    quad = (j + c) mod 8, j=0..31 -> perfect 4-way = the 512B minimum.
//  - 132*4 = 528 ≡ 0 mod 16: row starts 16B-aligned (R13).
// Pad cols 8m+6,7 are NEVER written: garbage there flows only into t2/t3
// of odd-c update threads, which owners (h==1) discard.
#define GPAD 132

__global__
__attribute__((amdgpu_flat_work_group_size(TPB, TPB), amdgpu_waves_per_eu(4, 4)))
void sgd_filter(const float* __restrict__ sos_in,
                const float* __restrict__ target,
                float* __restrict__ out) {
    // 16 sections x 6 floats, PAIRED: [b0 a0 b1 a1 b2 a2] per section.
    __shared__ __align__(16) float sos[96];
    // 128 rows (row = 2*(tid>>4) + quad-parity, a 4-freq group); section
    // blocks of 8 cols at 8*(4*sl+pos): [b0 a0 b1 a1 b2 a2 - -].
    __shared__ __align__(16) float gpart[128][GPAD];

    const int tid = threadIdx.x;
    const int qd  = tid >> 2;      // freq group: freqs 2qd, 2qd+1
    const int pos = tid & 3;       // section group: 4*pos .. 4*pos+3
    const float* secbase = &sos[pos * 24];

    if (tid < 96) sos[(tid / 6) * 6 + cmap(tid % 6)] = sos_in[tid];

    // Update identity (R7): thread (c = tid>>5 coeff-quad, j = tid&31 row
    // slice); ALL 16 waves participate. Owner lanes 31/63 hold 4 running
    // coefficients in registers. slot = c>>1 -> section 4*(slot&3)+(slot>>2);
    // h = c&1 selects (b0,a0,b1,a1) vs (b2,a2,-,-).
    const int c    = tid >> 5;
    const int j    = tid & 31;
    const int slot = c >> 1;
    const int h    = c & 1;
    const int us   = 4 * (slot & 3) + (slot >> 2);
    const bool owner = ((tid & 31) == 31);
    const float* urp = &gpart[j][4 * c];
    float k0 = 0.f, k1 = 0.f, k2 = 0.f, k3 = 0.f;
    if (owner) {
        if (h == 0) {
            k0 = sos_in[6 * us + 0]; k1 = sos_in[6 * us + 3];
            k2 = sos_in[6 * us + 1]; k3 = sos_in[6 * us + 4];
        } else {
            k0 = sos_in[6 * us + 2]; k1 = sos_in[6 * us + 5];
        }
    }

    // Per-thread frequency constants (two freqs)
    const double step = 3.14159265358979323846 / 511.0;
    const float w0 = (float)((double)(2 * qd) * step);
    const float w1 = (float)((double)(2 * qd + 1) * step);
    const float c10 = cosf(w0), s10 = -sinf(w0);
    const float c20 = c10 * c10 - s10 * s10, s20 = 2.0f * c10 * s10;
    const float c11 = cosf(w1), s11 = -sinf(w1);
    const float c21 = c11 * c11 - s11 * s11, s21 = 2.0f * c11 * s11;
    const float2 tg = *(const float2*)&target[2 * qd];
    const float KC = 40.0f / (512.0f * 2.302585092994046f); // 40/(n*ln10)

    const v2f c1v0 = mk2(c10, c10), s1v0 = mk2(s10, s10);
    const v2f c2v0 = mk2(c20, c20), s2v0 = mk2(s20, s20);
    const v2f c1v1 = mk2(c11, c11), s1v1 = mk2(s11, s11);
    const v2f c2v1 = mk2(c21, c21), s2v1 = mk2(s21, s21);

    __syncthreads();

    // 4 sections x 2 freqs: Re, Im, n; W = K/n after folded recovery.
    v2f RA0, RA1, RA2, RA3, IA0, IA1, IA2, IA3;
    v2f RB0, RB1, RB2, RB3, IB0, IB1, IB2, IB3;
    v2f NA0, NA1, NA2, NA3, NB0, NB1, NB2, NB3;

// One section, BOTH freqs (coefficient pair regs shared). n kept; no rcp.
#define SEC_EVAL(sl, BA0, BA1, BA2)                                         \
    {                                                                       \
        const v2f ba0 = BA0, ba1 = BA1, ba2 = BA2;                          \
        RA##sl = fma2(ba2, c2v0, fma2(ba1, c1v0, ba0));                     \
        IA##sl = fma2(ba2, s2v0, ba1 * s1v0);                               \
        NA##sl = fma2(RA##sl, RA##sl, IA##sl * IA##sl);                     \
        RB##sl = fma2(ba2, c2v1, fma2(ba1, c1v1, ba0));                     \
        IB##sl = fma2(ba2, s2v1, ba1 * s1v1);                               \
        NB##sl = fma2(RB##sl, RB##sl, IB##sl * IB##sl);                     \
    }

// Backward: W = K/n folded (R7) -> per freq just P = W*R, Q = W*I;
// freq-pair combine. R9: G1/G2 as 4-deep fma chains (4 insts each, was 5);
// exact same sum, associativity unchanged within each fma chain? -- NOTE:
// chain order is (((s1v0*QA) +fma c1v0*PA) +fma s1v1*QB) +fma c1v1*PB,
// a pure reorder of a 4-term sum (reduction-reorder class, absorbed).
// ONE stride-8 DPP per value. Writers = lanes (tid&15)>=8; row =
// 2*(tid>>4)+quad-parity; col block 8*(4*sl+pos). ALIGNED f4+f2 stores.
#define SEC_BWD(sl)                                                         \
    {                                                                       \
        const v2f PA = WA##sl * RA##sl;                                     \
        const v2f QA = WA##sl * IA##sl;                                     \
        const v2f PB = WB##sl * RB##sl;                                     \
        const v2f QB = WB##sl * IB##sl;                                     \
        const v2f P  = PA + PB;                                             \
        const v2f G1 = fma2(c1v1, PB, fma2(s1v1, QB,                        \
                       fma2(c1v0, PA, s1v0 * QA)));                         \
        const v2f G2 = fma2(c2v1, PB, fma2(s2v1, QB,                        \
                       fma2(c2v0, PA, s2v0 * QA)));                         \
        float g0, g1, g2, g3, g4, g5;                                       \
        red6_s8(P.x, G1.x, G2.x, P.y, G1.y, G2.y,                           \
                g0, g1, g2, g3, g4, g5);                                    \
        if ((tid & 15) >= 8) {                                              \
            float* p = &gpart[((tid >> 4) << 1) | ((tid >> 2) & 1)]         \
                             [8 * (4 * (sl) + pos)];                        \
            *(float4*)p       = make_float4(g0, g3, g1, g4);                \
            *(float2*)(p + 4) = make_float2(g2, g5);                        \
        }                                                                   \
    }

    for (int it = 0; it < 1000; ++it) {
        // ---- forward: 6 b128 broadcast loads cover my 4 sections ----
        const float4 q0 = *(const float4*)(secbase + 0);
        const float4 q1 = *(const float4*)(secbase + 4);
        const float4 q2 = *(const float4*)(secbase + 8);
        const float4 q3 = *(const float4*)(secbase + 12);
        const float4 q4 = *(const float4*)(secbase + 16);
        const float4 q5 = *(const float4*)(secbase + 20);
        SEC_EVAL(0, mk2(q0.x, q0.y), mk2(q0.z, q0.w), mk2(q1.x, q1.y))
        SEC_EVAL(1, mk2(q1.z, q1.w), mk2(q2.x, q2.y), mk2(q2.z, q2.w))
        SEC_EVAL(2, mk2(q3.x, q3.y), mk2(q3.z, q3.w), mk2(q4.x, q4.y))
        SEC_EVAL(3, mk2(q4.z, q4.w), mk2(q5.x, q5.y), mk2(q5.z, q5.w))

        // ---- products + reciprocal; L = log2(m.x * rcp(m.y)) (R7) ----
        const v2f tA01 = NA0 * NA1, tA23 = NA2 * NA3;
        const v2f mA   = tA01 * tA23;
        const v2f iA   = rcp2(mA);
        const v2f tB01 = NB0 * NB1, tB23 = NB2 * NB3;
        const v2f mB   = tB01 * tB23;
        const v2f iB   = rcp2(mB);
        float L0 = __builtin_amdgcn_logf(mA.x * iA.y);
        float L1 = __builtin_amdgcn_logf(mB.x * iB.y);

        // Quad butterfly: every lane gets the bit-identical 16-section total.
        quad_allsum2(L0, L1);

        // ---- EXACT R7 K-chain (eps kept — R8 lesson) ----
        const float mag0   = __builtin_amdgcn_exp2f(0.5f * L0);
        const float magpe0 = mag0 + 1e-8f;
        const float indB0  = 6.020599913279624f * __builtin_amdgcn_logf(magpe0);
        const float K0 = KC * (indB0 - tg.x) * mag0 * __builtin_amdgcn_rcpf(magpe0);
        const float mag1   = __builtin_amdgcn_exp2f(0.5f * L1);
        const float magpe1 = mag1 + 1e-8f;
        const float indB1  = 6.020599913279624f * __builtin_amdgcn_logf(magpe1);
        const float K1 = KC * (indB1 - tg.y) * mag1 * __builtin_amdgcn_rcpf(magpe1);
        const v2f KK0 = mk2(K0, -K0);   // A-side gradient sign folded here
        const v2f KK1 = mk2(K1, -K1);

        // ---- K folded into batched recovery: W = K/n per section ----
        const v2f jA   = KK0 * iA;
        const v2f jA01 = jA * tA23, jA23 = jA * tA01;
        const v2f WA0 = jA01 * NA1, WA1 = jA01 * NA0;
        const v2f WA2 = jA23 * NA3, WA3 = jA23 * NA2;
        const v2f jB   = KK1 * iB;
        const v2f jB01 = jB * tB23, jB23 = jB * tB01;
        const v2f WB0 = jB01 * NB1, WB1 = jB01 * NB0;
        const v2f WB2 = jB23 * NB3, WB3 = jB23 * NB2;

        // ---- backward: 4 sections, freq-pair add + 1-stage DPP, store ----
        SEC_BWD(0) SEC_BWD(1) SEC_BWD(2) SEC_BWD(3)
        __syncthreads();

        // ---- update (R7/R9): ALL 16 waves; 4 b128 reads (rows j+32i,
        //      col 4c, perfect 4-way), packed v4f tree-sum (6 pk adds),
        //      32-lane DPP ladder; owner lanes 31/63 apply SGD in-register
        //      and write sos as f2s ----
        {
            const v4f p0 = *(const v4f*)urp;
            const v4f p1 = *(const v4f*)(urp + 32 * GPAD);
            const v4f p2 = *(const v4f*)(urp + 64 * GPAD);
            const v4f p3 = *(const v4f*)(urp + 96 * GPAD);
            const v4f s = (p0 + p1) + (p2 + p3);
            float t0 = s.x, t1 = s.y, t2 = s.z, t3 = s.w;
            red4_g32(t0, t1, t2, t3);
            if (owner) {
                k0 = fmaf(-0.1f, t0, k0);
                k1 = fmaf(-0.1f, t1, k1);
                k2 = fmaf(-0.1f, t2, k2);
                k3 = fmaf(-0.1f, t3, k3);
                if (h == 0) {
                    *(float2*)&sos[6 * us]     = make_float2(k0, k1);
                    *(float2*)&sos[6 * us + 2] = make_float2(k2, k3);
                } else {
                    *(float2*)&sos[6 * us + 4] = make_float2(k0, k1);
                }
            }
        }
        __syncthreads();
    }

    if (owner) {
        if (h == 0) {
            out[6 * us + 0] = k0; out[6 * us + 3] = k1;
            out[6 * us + 1] = k2; out[6 * us + 4] = k3;
        } else {
            out[6 * us + 2] = k0; out[6 * us + 5] = k1;
        }
    }
}

extern "C" void kernel_launch(void* const* d_in, const int* in_sizes, int n_in,
                              void* d_out, int out_size, void* d_ws, size_t ws_size,
                              hipStream_t stream) {
    const float* sos_in = (const float*)d_in[0];
    const float* target = (const float*)d_in[1];
    float* outp = (float*)d_out;
    hipLaunchKernelGGL(sgd_filter, dim3(1), dim3(TPB), 0, stream, sos_in, target, outp);
}

// Round 10
// 1851.218 us; speedup vs baseline: 1.0978x; 1.0589x over previous
//
#include <hip/hip_runtime.h>
#include <math.h>

#define TPB 1024   // 16 waves = 4/SIMD. QUAD LAYOUT (R5): thread =
                   // (qd = tid>>2 -> freqs 2qd,2qd+1 ; pos = tid&3 ->
                   // sections 4*pos..4*pos+3). 2 barriers/iter.
                   // R10: mag via PRODUCT-domain quad butterfly + v_sqrt
                   // (kills 2 logs + 2 exp2; eps chain kept EXACTLY, R8
                   // lesson). gpart col = 6*sec + paired-k, contiguous:
                   // backward = 6 aligned f4 stores; update = 24 c-quads,
                   // owner writes ONE f4 to sos.

typedef float v2f __attribute__((ext_vector_type(2)));
typedef float v4f __attribute__((ext_vector_type(4)));

static __device__ __forceinline__ v2f mk2(float x, float y) {
    v2f r; r.x = x; r.y = y; return r;
}
// Compiler-generated packed math only — NO hand-written v_pk_* asm (R5/R7).
static __device__ __forceinline__ v2f fma2(v2f a, v2f b, v2f c) {
    return __builtin_elementwise_fma(a, b, c);
}
// RAW v_rcp_f32 (~1 ulp): NR dropped (R16). R6 batches 4 section inverses
// through ONE product reciprocal (prefix/suffix recovery). R7 folds K into
// the recovery. The dB chain keeps its 1e-8 eps EXACTLY (R8 lesson).
static __device__ __forceinline__ v2f rcp2(v2f x) {
    v2f r;
    r.x = __builtin_amdgcn_rcpf(x.x);
    r.y = __builtin_amdgcn_rcpf(x.y);
    return r;
}

// Quad all-PRODUCT of TWO independent values (R10): xor1 then xor2 with
// v_mul DPP. ALL 4 lanes end with the bit-identical product (pairwise
// tree + commutative muls). s_nops cover DPP read-after-VALU, same
// spacing pattern as the R5-validated quad_allsum2.
static __device__ __forceinline__ void quad_allprod2(float& a, float& b) {
    asm("s_nop 1\n\t"
        "v_mul_f32 %0, %0, %0 quad_perm:[1,0,3,2] row_mask:0xf bank_mask:0xf bound_ctrl:0\n\t"
        "v_mul_f32 %1, %1, %1 quad_perm:[1,0,3,2] row_mask:0xf bank_mask:0xf bound_ctrl:0\n\t"
        "s_nop 0\n\t"
        "v_mul_f32 %0, %0, %0 quad_perm:[2,3,0,1] row_mask:0xf bank_mask:0xf bound_ctrl:0\n\t"
        "v_mul_f32 %1, %1, %1 quad_perm:[2,3,0,1] row_mask:0xf bank_mask:0xf bound_ctrl:0"
        : "+v"(a), "+v"(b));
}

// SINGLE-stage cross-quad combine (R6): lanes l>=8 of each 16-row get
// v(l)+v(l-8): lanes 8..11 = quads{0,2}, 12..15 = quads{1,3} of the row.
__device__ __forceinline__ void red6_s8(float i0, float i1, float i2,
                                        float i3, float i4, float i5,
                                        float& o0, float& o1, float& o2,
                                        float& o3, float& o4, float& o5) {
    asm("s_nop 1\n\t"
        "v_add_f32 %0, %6, %6  row_shr:8 row_mask:0xf bank_mask:0xf bound_ctrl:0\n\t"
        "v_add_f32 %3, %9, %9  row_shr:8 row_mask:0xf bank_mask:0xf bound_ctrl:0\n\t"
        "v_add_f32 %1, %7, %7  row_shr:8 row_mask:0xf bank_mask:0xf bound_ctrl:0\n\t"
        "v_add_f32 %4, %10, %10 row_shr:8 row_mask:0xf bank_mask:0xf bound_ctrl:0\n\t"
        "v_add_f32 %2, %8, %8  row_shr:8 row_mask:0xf bank_mask:0xf bound_ctrl:0\n\t"
        "v_add_f32 %5, %11, %11 row_shr:8 row_mask:0xf bank_mask:0xf bound_ctrl:0"
        : "=&v"(o0), "=&v"(o1), "=&v"(o2), "=&v"(o3), "=&v"(o4), "=&v"(o5)
        : "v"(i0), "v"(i1), "v"(i2), "v"(i3), "v"(i4), "v"(i5));
}

// 32-lane-group reduction of FOUR values (R7 update): shr:1,2,4,8 then
// row_bcast:15 (row_mask 0xa: rows 1,3 receive lanes 15/47). Lanes 31 and
// 63 end with their 32-group totals. Round-robin -> 4-inst hazard spacing.
__device__ __forceinline__ void red4_g32(float& a, float& b,
                                         float& c, float& d) {
    asm("s_nop 1\n\t"
        "v_add_f32 %0, %0, %0 row_shr:1 row_mask:0xf bank_mask:0xf bound_ctrl:0\n\t"
        "v_add_f32 %1, %1, %1 row_shr:1 row_mask:0xf bank_mask:0xf bound_ctrl:0\n\t"
        "v_add_f32 %2, %2, %2 row_shr:1 row_mask:0xf bank_mask:0xf bound_ctrl:0\n\t"
        "v_add_f32 %3, %3, %3 row_shr:1 row_mask:0xf bank_mask:0xf bound_ctrl:0\n\t"
        "v_add_f32 %0, %0, %0 row_shr:2 row_mask:0xf bank_mask:0xf bound_ctrl:0\n\t"
        "v_add_f32 %1, %1, %1 row_shr:2 row_mask:0xf bank_mask:0xf bound_ctrl:0\n\t"
        "v_add_f32 %2, %2, %2 row_shr:2 row_mask:0xf bank_mask:0xf bound_ctrl:0\n\t"
        "v_add_f32 %3, %3, %3 row_shr:2 row_mask:0xf bank_mask:0xf bound_ctrl:0\n\t"
        "v_add_f32 %0, %0, %0 row_shr:4 row_mask:0xf bank_mask:0xf bound_ctrl:0\n\t"
        "v_add_f32 %1, %1, %1 row_shr:4 row_mask:0xf bank_mask:0xf bound_ctrl:0\n\t"
        "v_add_f32 %2, %2, %2 row_shr:4 row_mask:0xf bank_mask:0xf bound_ctrl:0\n\t"
        "v_add_f32 %3, %3, %3 row_shr:4 row_mask:0xf bank_mask:0xf bound_ctrl:0\n\t"
        "v_add_f32 %0, %0, %0 row_shr:8 row_mask:0xf bank_mask:0xf bound_ctrl:0\n\t"
        "v_add_f32 %1, %1, %1 row_shr:8 row_mask:0xf bank_mask:0xf bound_ctrl:0\n\t"
        "v_add_f32 %2, %2, %2 row_shr:8 row_mask:0xf bank_mask:0xf bound_ctrl:0\n\t"
        "v_add_f32 %3, %3, %3 row_shr:8 row_mask:0xf bank_mask:0xf bound_ctrl:0\n\t"
        "v_add_f32 %0, %0, %0 row_bcast:15 row_mask:0xa bank_mask:0xf\n\t"
        "v_add_f32 %1, %1, %1 row_bcast:15 row_mask:0xa bank_mask:0xf\n\t"
        "v_add_f32 %2, %2, %2 row_bcast:15 row_mask:0xa bank_mask:0xf\n\t"
        "v_add_f32 %3, %3, %3 row_bcast:15 row_mask:0xa bank_mask:0xf"
        : "+v"(a), "+v"(b), "+v"(c), "+v"(d));
}

// coefficient k (0..5 = b0,b1,b2,a0,a1,a2) -> paired column in
// [b0 a0 b1 a1 b2 a2]: b0,b1,b2 -> 0,2,4 ; a0,a1,a2 -> 1,3,5
__device__ __forceinline__ int cmap(int k) {
    return (k < 3) ? 2 * k : 2 * k - 5;
}
// inverse: paired index p -> original k: even p -> p/2 (b), odd -> 3+p/2 (a)
__device__ __forceinline__ int oidx(int cid) {
    const int s = cid / 6, p = cid % 6;
    return 6 * s + ((p & 1) ? 3 + (p >> 1) : (p >> 1));
}

// GPAD=100 (per 32-LANE-PHASE bank derivation; 100/4=25≡1 mod 8 so
// quad = (row + col/4) mod 8):
//  - backward f4 stores (16 writers/phase: rows 0..3 x pos 0..3, f4 #m at
//    col 24*pos+4m): quad = (row + 6*pos + m) mod 8 -> multiset
//    {0..3}+{0,6,12,18} mod 8 = each quad exactly 2x = sweep MINIMUM.
//    Base 96*pos bytes ≡ 0 mod 16: aligned (R13).
//  - update b128 reads (col 4c, c uniform per phase, rows j..j+96):
//    quad = (j + c) mod 8, j=0..31 -> perfect 4-way = the 512B minimum.
//  - 100*4 = 400 ≡ 0 mod 16: row starts aligned (R13).
#define GPAD 100

__global__
__attribute__((amdgpu_flat_work_group_size(TPB, TPB), amdgpu_waves_per_eu(4, 4)))
void sgd_filter(const float* __restrict__ sos_in,
                const float* __restrict__ target,
                float* __restrict__ out) {
    // 16 sections x 6 floats, PAIRED: col = cid = 6*sec + paired-k.
    __shared__ __align__(16) float sos[96];
    // 128 rows (row = 2*(tid>>4) + quad-parity, a 4-freq group);
    // col = cid 0..95, fully contiguous (R10 — no pads).
    __shared__ __align__(16) float gpart[128][GPAD];

    const int tid = threadIdx.x;
    const int qd  = tid >> 2;      // freq group: freqs 2qd, 2qd+1
    const int pos = tid & 3;       // section group: 4*pos .. 4*pos+3
    const float* secbase = &sos[pos * 24];
    const int brow = ((tid >> 4) << 1) | ((tid >> 2) & 1);  // backward row

    if (tid < 96) sos[(tid / 6) * 6 + cmap(tid % 6)] = sos_in[tid];

    // Update identity (R10): c = tid>>5 coeff-quad (0..23 used), j = tid&31
    // row slice; 12 waves active, owner = lane 31 of each group holds the
    // 4 running coefficients cid = 4c..4c+3 in registers.
    const int c    = tid >> 5;
    const int j    = tid & 31;
    const bool upd   = (c < 24);
    const bool owner = upd && (j == 31);
    const float* urp = &gpart[j][4 * (c & 31)];
    const int oi0 = oidx(4 * c + 0), oi1 = oidx(4 * c + 1);
    const int oi2 = oidx(4 * c + 2), oi3 = oidx(4 * c + 3);
    float k0 = 0.f, k1 = 0.f, k2 = 0.f, k3 = 0.f;
    if (owner) {
        k0 = sos_in[oi0]; k1 = sos_in[oi1];
        k2 = sos_in[oi2]; k3 = sos_in[oi3];
    }

    // Per-thread frequency constants (two freqs)
    const double step = 3.14159265358979323846 / 511.0;
    const float w0 = (float)((double)(2 * qd) * step);
    const float w1 = (float)((double)(2 * qd + 1) * step);
    const float c10 = cosf(w0), s10 = -sinf(w0);
    const float c20 = c10 * c10 - s10 * s10, s20 = 2.0f * c10 * s10;
    const float c11 = cosf(w1), s11 = -sinf(w1);
    const float c21 = c11 * c11 - s11 * s11, s21 = 2.0f * c11 * s11;
    const float2 tg = *(const float2*)&target[2 * qd];
    const float KC = 40.0f / (512.0f * 2.302585092994046f); // 40/(n*ln10)
    // R10: K = (A2*log2(magpe) + nKt) * mag * rcp(magpe) — pure
    // reassociation of KC*(6.0206*log2(magpe) - tg)*mag*rcp(magpe).
    const float A2   = KC * 6.020599913279624f;
    const float nKt0 = -KC * tg.x;
    const float nKt1 = -KC * tg.y;

    const v2f c1v0 = mk2(c10, c10), s1v0 = mk2(s10, s10);
    const v2f c2v0 = mk2(c20, c20), s2v0 = mk2(s20, s20);
    const v2f c1v1 = mk2(c11, c11), s1v1 = mk2(s11, s11);
    const v2f c2v1 = mk2(c21, c21), s2v1 = mk2(s21, s21);

    __syncthreads();

    // 4 sections x 2 freqs: Re, Im, n; W = K/n after folded recovery.
    v2f RA0, RA1, RA2, RA3, IA0, IA1, IA2, IA3;
    v2f RB0, RB1, RB2, RB3, IB0, IB1, IB2, IB3;
    v2f NA0, NA1, NA2, NA3, NB0, NB1, NB2, NB3;

// One section, BOTH freqs (coefficient pair regs shared). n kept; no rcp.
#define SEC_EVAL(sl, BA0, BA1, BA2)                                         \
    {                                                                       \
        const v2f ba0 = BA0, ba1 = BA1, ba2 = BA2;                          \
        RA##sl = fma2(ba2, c2v0, fma2(ba1, c1v0, ba0));                     \
        IA##sl = fma2(ba2, s2v0, ba1 * s1v0);                               \
        NA##sl = fma2(RA##sl, RA##sl, IA##sl * IA##sl);                     \
        RB##sl = fma2(ba2, c2v1, fma2(ba1, c1v1, ba0));                     \
        IB##sl = fma2(ba2, s2v1, ba1 * s1v1);                               \
        NB##sl = fma2(RB##sl, RB##sl, IB##sl * IB##sl);                     \
    }

// Backward: W = K/n folded (R7) -> per freq just P = W*R, Q = W*I;
// freq-pair combine; G1/G2 as 4-deep fma chains (R9, reorder class);
// ONE stride-8 DPP per value. Outputs g##0..g##5 = (b0,b1,b2,a0,a1,a2)
// kept in registers; all 4 sections stored together afterwards (R10).
#define SEC_BWD(sl, g)                                                      \
    float g##0, g##1, g##2, g##3, g##4, g##5;                               \
    {                                                                       \
        const v2f PA = WA##sl * RA##sl;                                     \
        const v2f QA = WA##sl * IA##sl;                                     \
        const v2f PB = WB##sl * RB##sl;                                     \
        const v2f QB = WB##sl * IB##sl;                                     \
        const v2f P  = PA + PB;                                             \
        const v2f G1 = fma2(c1v1, PB, fma2(s1v1, QB,                        \
                       fma2(c1v0, PA, s1v0 * QA)));                         \
        const v2f G2 = fma2(c2v1, PB, fma2(s2v1, QB,                        \
                       fma2(c2v0, PA, s2v0 * QA)));                         \
        red6_s8(P.x, G1.x, G2.x, P.y, G1.y, G2.y,                           \
                g##0, g##1, g##2, g##3, g##4, g##5);                        \
    }

    for (int it = 0; it < 1000; ++it) {
        // ---- forward: 6 b128 broadcast loads cover my 4 sections ----
        const float4 q0 = *(const float4*)(secbase + 0);
        const float4 q1 = *(const float4*)(secbase + 4);
        const float4 q2 = *(const float4*)(secbase + 8);
        const float4 q3 = *(const float4*)(secbase + 12);
        const float4 q4 = *(const float4*)(secbase + 16);
        const float4 q5 = *(const float4*)(secbase + 20);
        SEC_EVAL(0, mk2(q0.x, q0.y), mk2(q0.z, q0.w), mk2(q1.x, q1.y))
        SEC_EVAL(1, mk2(q1.z, q1.w), mk2(q2.x, q2.y), mk2(q2.z, q2.w))
        SEC_EVAL(2, mk2(q3.x, q3.y), mk2(q3.z, q3.w), mk2(q4.x, q4.y))
        SEC_EVAL(3, mk2(q4.z, q4.w), mk2(q5.x, q5.y), mk2(q5.z, q5.w))

        // ---- products + reciprocal; per-thread ratio = |B|^2/|A|^2 over
        //      my 4 sections (R10: linear domain, no logs) ----
        const v2f tA01 = NA0 * NA1, tA23 = NA2 * NA3;
        const v2f mA   = tA01 * tA23;
        const v2f iA   = rcp2(mA);
        const v2f tB01 = NB0 * NB1, tB23 = NB2 * NB3;
        const v2f mB   = tB01 * tB23;
        const v2f iB   = rcp2(mB);
        float r0 = mA.x * iA.y;
        float r1 = mB.x * iB.y;

        // Quad butterfly in PRODUCT domain: every lane gets the
        // bit-identical 16-section |H|^2 for both of its freqs.
        quad_allprod2(r0, r1);

        // ---- K-chain: mag = sqrt(|H|^2); eps chain EXACT (R8 lesson) ----
        const float mag0   = __builtin_amdgcn_sqrtf(r0);
        const float magpe0 = mag0 + 1e-8f;
        const float t0c    = fmaf(A2, __builtin_amdgcn_logf(magpe0), nKt0);
        const float K0     = t0c * mag0 * __builtin_amdgcn_rcpf(magpe0);
        const float mag1   = __builtin_amdgcn_sqrtf(r1);
        const float magpe1 = mag1 + 1e-8f;
        const float t1c    = fmaf(A2, __builtin_amdgcn_logf(magpe1), nKt1);
        const float K1     = t1c * mag1 * __builtin_amdgcn_rcpf(magpe1);
        const v2f KK0 = mk2(K0, -K0);   // A-side gradient sign folded here
        const v2f KK1 = mk2(K1, -K1);

        // ---- K folded into batched recovery: W = K/n per section ----
        const v2f jA   = KK0 * iA;
        const v2f jA01 = jA * tA23, jA23 = jA * tA01;
        const v2f WA0 = jA01 * NA1, WA1 = jA01 * NA0;
        const v2f WA2 = jA23 * NA3, WA3 = jA23 * NA2;
        const v2f jB   = KK1 * iB;
        const v2f jB01 = jB * tB23, jB23 = jB * tB01;
        const v2f WB0 = jB01 * NB1, WB1 = jB01 * NB0;
        const v2f WB2 = jB23 * NB3, WB3 = jB23 * NB2;

        // ---- backward: 4 sections reduced, then 6 aligned f4 stores of
        //      24 contiguous floats at col 24*pos (2-way banks, minimum) --
        SEC_BWD(0, ga) SEC_BWD(1, gb) SEC_BWD(2, gc) SEC_BWD(3, gd)
        if ((tid & 15) >= 8) {
            float4* p = (float4*)&gpart[brow][24 * pos];
            p[0] = make_float4(ga0, ga3, ga1, ga4);
            p[1] = make_float4(ga2, ga5, gb0, gb3);
            p[2] = make_float4(gb1, gb4, gb2, gb5);
            p[3] = make_float4(gc0, gc3, gc1, gc4);
            p[4] = make_float4(gc2, gc5, gd0, gd3);
            p[5] = make_float4(gd1, gd4, gd2, gd5);
        }
        __syncthreads();

        // ---- update (R10): 24 c-quads x 32 lanes (12 waves); 4 b128 reads
        //      (perfect 4-way), packed v4f tree-sum, 32-lane DPP ladder;
        //      owner lane 31 applies SGD in-register, ONE f4 to sos ----
        if (upd) {
            const v4f p0 = *(const v4f*)urp;
            const v4f p1 = *(const v4f*)(urp + 32 * GPAD);
            const v4f p2 = *(const v4f*)(urp + 64 * GPAD);
            const v4f p3 = *(const v4f*)(urp + 96 * GPAD);
            const v4f s = (p0 + p1) + (p2 + p3);
            float t0 = s.x, t1 = s.y, t2 = s.z, t3 = s.w;
            red4_g32(t0, t1, t2, t3);
            if (owner) {
                k0 = fmaf(-0.1f, t0, k0);
                k1 = fmaf(-0.1f, t1, k1);
                k2 = fmaf(-0.1f, t2, k2);
                k3 = fmaf(-0.1f, t3, k3);
                *(float4*)&sos[4 * c] = make_float4(k0, k1, k2, k3);
            }
        }
        __syncthreads();
    }

    if (owner) {
        out[oi0] = k0; out[oi1] = k1;
        out[oi2] = k2; out[oi3] = k3;
    }
}

extern "C" void kernel_launch(void* const* d_in, const int* in_sizes, int n_in,
                              void* d_out, int out_size, void* d_ws, size_t ws_size,
                              hipStream_t stream) {
    const float* sos_in = (const float*)d_in[0];
    const float* target = (const float*)d_in[1];
    float* outp = (float*)d_out;
    hipLaunchKernelGGL(sgd_filter, dim3(1), dim3(TPB), 0, stream, sos_in, target, outp);
}